// Round 1
// 492.954 us; speedup vs baseline: 1.0131x; 1.0131x over previous
//
#include <hip/hip_runtime.h>
#include <hip/hip_bf16.h>

typedef unsigned short u16;
typedef short s16x8 __attribute__((ext_vector_type(8)));
typedef unsigned int u32x2 __attribute__((ext_vector_type(2)));
typedef float f32x4 __attribute__((ext_vector_type(4)));

#define F_DIM 2048
#define A_DIM 1024
#define H_DIM 1024
#define BATCH 128
#define LLEN  196
#define MROWS (BATCH * LLEN)   // 25088
#define MTILES (MROWS / 256)   // 98

__device__ __forceinline__ u16 f2b(float x) {
  union { float f; unsigned int u; } c; c.f = x;
  unsigned int r = (c.u + 0x7fffu + ((c.u >> 16) & 1u)) >> 16;  // RNE
  return (u16)r;
}

// gfx950-native packed fp32->bf16 (RNE): dst.lo16 = cvt(a), dst.hi16 = cvt(b)
__device__ __forceinline__ unsigned int f2b_pk(float a, float b) {
  unsigned int r;
  asm volatile("v_cvt_pk_bf16_f32 %0, %1, %2" : "=v"(r) : "v"(a), "v"(b));
  return r;
}

__device__ __forceinline__ void gload_lds16(const void* g, void* l) {
  __builtin_amdgcn_global_load_lds((const __attribute__((address_space(1))) void*)g,
                                   (__attribute__((address_space(3))) void*)l, 16, 0, 0);
}

// ---------------------------------------------------------------------------
// K0: W_enc (2048x1024 fp32, k-major) -> WT (1024x2048 bf16, a-major)
__global__ void wenc_cvt_kernel(const float* __restrict__ W, u16* __restrict__ WT) {
  __shared__ float tile[32][33];
  int kb = blockIdx.x * 32, ab = blockIdx.y * 32;
  int t = threadIdx.x;
  int r = t >> 3, c = (t & 7) * 4;
  float4 v = *(const float4*)&W[(size_t)(kb + r) * A_DIM + ab + c];
  tile[r][c] = v.x; tile[r][c + 1] = v.y; tile[r][c + 2] = v.z; tile[r][c + 3] = v.w;
  __syncthreads();
  ushort4 o;
  o.x = f2b(tile[c + 0][r]);
  o.y = f2b(tile[c + 1][r]);
  o.z = f2b(tile[c + 2][r]);
  o.w = f2b(tile[c + 3][r]);
  *(ushort4*)&WT[(size_t)(ab + r) * F_DIM + kb + c] = o;
}

// ---------------------------------------------------------------------------
// K1: attn2p[b][a] = hidden[b]·W_hid[:,a] + b_hid[a] + b_enc[a]  (k-split 8, atomic)
__global__ void attn2_kernel(const float* __restrict__ hidden, const float* __restrict__ W_hid,
                             const float* __restrict__ b_hid, const float* __restrict__ b_enc,
                             float* __restrict__ attn2p) {
  __shared__ float hl[8][128];
  int t = threadIdx.x;
  int a  = blockIdx.x * 256 + t;
  int b0 = blockIdx.y * 8;
  int k0 = blockIdx.z * 128;
  {
    int j = t >> 5, kk = (t & 31) * 4;
    float4 v = *(const float4*)&hidden[(size_t)(b0 + j) * H_DIM + k0 + kk];
    hl[j][kk + 0] = v.x; hl[j][kk + 1] = v.y; hl[j][kk + 2] = v.z; hl[j][kk + 3] = v.w;
  }
  __syncthreads();
  float acc[8] = {0.f, 0.f, 0.f, 0.f, 0.f, 0.f, 0.f, 0.f};
  #pragma unroll 4
  for (int k = 0; k < 128; ++k) {
    float w = W_hid[(size_t)(k0 + k) * A_DIM + a];
    #pragma unroll
    for (int j = 0; j < 8; ++j) acc[j] = fmaf(hl[j][k], w, acc[j]);
  }
  if (blockIdx.z == 0) {
    float bias = b_hid[a] + b_enc[a];
    #pragma unroll
    for (int j = 0; j < 8; ++j) acc[j] += bias;
  }
  #pragma unroll
  for (int j = 0; j < 8; ++j) atomicAdd(&attn2p[(size_t)(b0 + j) * A_DIM + a], acc[j]);
}

// ---------------------------------------------------------------------------
// K2: fused GEMM + score. 256x256 tile, BK=32, 8 waves (2M x 4N), wave tile
// 128x64 (acc[8][4]). HK-style pipeline in plain HIP:
//  - A (enc fp32): T14 reg-staging: global_load_dwordx4 issued 4 tiles ahead,
//    v_cvt_pk_bf16_f32 + ds_write_b64 2 tiles ahead (cvt once per element,
//    bf16 in LDS -> half the LDS read traffic vs fp32-A).
//  - B (WT bf16): global_load_lds width-16, source pre-swizzled.
//  - 4-deep LDS buffers (128 KiB), ONE raw s_barrier per K-tile, counted
//    s_waitcnt vmcnt(6) (never 0 in the loop): loads span barriers (T4).
//  - T2 XOR swizzle on both tiles: granule ^= (row>>1)&3 -> 2-way (free) on
//    ds_read_b128.
//  - T5 setprio(1) around the 32-MFMA cluster.
//  - Tail: source k-index clamped so issue counts stay uniform (dummy
//    re-stages of tile 63 land in already-consumed buffers).
// Grid: 13 groups x (4 n x 8 m); blocks sharing an A-slab have equal id%8
// -> same XCD L2.
__global__ __launch_bounds__(512, 2) void gemm_score(
    const float* __restrict__ enc, const u16* __restrict__ WT,
    const float* __restrict__ attn2p, const float* __restrict__ W_full,
    float* __restrict__ scores) {
  __shared__ __align__(16) u16 As[4 * 8192];   // 4 bufs x 256 rows x 32 k bf16 = 64 KB
  __shared__ __align__(16) u16 Bs[4 * 8192];   // 64 KB

  int i = blockIdx.x;
  int g = i >> 5, r = i & 31;
  int y = r >> 3, gi = r & 7;
  int mt = g * 8 + gi;
  if (mt >= MTILES) return;
  int m0 = mt * 256, n0 = y * 256;
  int t = threadIdx.x;
  int lane = t & 63, wave = t >> 6;
  int wr = wave >> 2, wc = wave & 3;   // wave grid 2M x 4N
  int c16 = lane & 15, quad = lane >> 4;

  // A global: thread t loads rows (t>>3)+64*ii, floats (t&7)*4.. (4x dwordx4,
  // each row's 128B k-slice read by 8 contiguous lanes).
  const float* aP = enc + (size_t)(m0 + (t >> 3)) * F_DIM + (t & 7) * 4;
  // A ds_write: row (t>>3)+64*ii, granule (t&7)>>1 XOR-swizzled, half (t&7)&1.
  // swizzle key (row>>1)&3 is ii-invariant (64*ii == 0 mod 4 after >>1).
  const int awoff = (t >> 3) * 32 + ((((t & 7) >> 1) ^ (((t >> 3) >> 1) & 3)) * 8)
                  + ((t & 7) & 1) * 4;
  // B gload: site s covers rows s*128 + (t>>2); source granule pre-swizzled.
  const u16* bP = WT + (size_t)(n0 + (t >> 2)) * F_DIM + ((t & 3) ^ ((t >> 3) & 3)) * 8;
  const int bw512 = wave * 512;   // per-wave LDS dest base (u16)

  // fragment read offsets (u16): row*32 + (quad ^ (c16>>1)&3)*8
  const int akey = (c16 >> 1) & 3;
  const int aroff = (wr * 128 + c16) * 32 + (quad ^ akey) * 8;
  const int broff = (wc * 64 + c16) * 32 + (quad ^ akey) * 8;

  f32x4 acc[8][4];
  #pragma unroll
  for (int mi = 0; mi < 8; ++mi)
    #pragma unroll
    for (int ni = 0; ni < 4; ++ni) acc[mi][ni] = (f32x4){0.f, 0.f, 0.f, 0.f};

  float4 R0[4], R1[4];

  // ---- prologue: stage tiles 0,1; issue A-loads for tiles 2,3; drain once.
  #pragma unroll
  for (int ii = 0; ii < 4; ++ii) R0[ii] = *(const float4*)(aP + (size_t)ii * 64 * F_DIM);
  #pragma unroll
  for (int ii = 0; ii < 4; ++ii) R1[ii] = *(const float4*)(aP + (size_t)ii * 64 * F_DIM + 32);
  gload_lds16(bP, &Bs[bw512]);
  gload_lds16(bP + (size_t)128 * F_DIM, &Bs[4096 + bw512]);
  gload_lds16(bP + 32, &Bs[8192 + bw512]);
  gload_lds16(bP + (size_t)128 * F_DIM + 32, &Bs[8192 + 4096 + bw512]);
  #pragma unroll
  for (int ii = 0; ii < 4; ++ii) {
    u32x2 w; w.x = f2b_pk(R0[ii].x, R0[ii].y); w.y = f2b_pk(R0[ii].z, R0[ii].w);
    *(u32x2*)&As[awoff + ii * 2048] = w;
  }
  #pragma unroll
  for (int ii = 0; ii < 4; ++ii) {
    u32x2 w; w.x = f2b_pk(R1[ii].x, R1[ii].y); w.y = f2b_pk(R1[ii].z, R1[ii].w);
    *(u32x2*)&As[8192 + awoff + ii * 2048] = w;
  }
  #pragma unroll
  for (int ii = 0; ii < 4; ++ii) R0[ii] = *(const float4*)(aP + (size_t)ii * 64 * F_DIM + 64);
  #pragma unroll
  for (int ii = 0; ii < 4; ++ii) R1[ii] = *(const float4*)(aP + (size_t)ii * 64 * F_DIM + 96);
  asm volatile("s_waitcnt vmcnt(0) lgkmcnt(0)" ::: "memory");  // one-time drain
  __builtin_amdgcn_s_barrier();

  // ---- main loop: 64 K-tiles. TILE(J): read buf J, write buf (J+2)&3,
  // RX holds A(p+2) fp32 on entry; reissued for A(p+4).
#define TILE(J, RX) do {                                                        \
    const int rb_ = (J) * 8192;                                                 \
    const int wb_ = (((J) + 2) & 3) * 8192;                                     \
    int p_ = kt + (J);                                                          \
    int kts_ = min(p_ + 2, 63);                                                 \
    int ktl_ = min(p_ + 4, 63);                                                 \
    _Pragma("unroll")                                                           \
    for (int ii = 0; ii < 4; ++ii) {                                            \
      u32x2 w_; w_.x = f2b_pk(RX[ii].x, RX[ii].y);                              \
      w_.y = f2b_pk(RX[ii].z, RX[ii].w);                                        \
      *(u32x2*)&As[wb_ + awoff + ii * 2048] = w_;                               \
    }                                                                           \
    _Pragma("unroll")                                                           \
    for (int ii = 0; ii < 4; ++ii)                                              \
      RX[ii] = *(const float4*)(aP + (size_t)ii * 64 * F_DIM + ktl_ * 32);      \
    gload_lds16(bP + (size_t)kts_ * 32, &Bs[wb_ + bw512]);                      \
    gload_lds16(bP + (size_t)128 * F_DIM + (size_t)kts_ * 32,                   \
                &Bs[wb_ + 4096 + bw512]);                                       \
    {                                                                           \
      s16x8 af_[8], bf_[4];                                                     \
      _Pragma("unroll")                                                         \
      for (int ni = 0; ni < 4; ++ni)                                            \
        bf_[ni] = *(const s16x8*)&Bs[rb_ + broff + ni * 512];                   \
      _Pragma("unroll")                                                         \
      for (int mi = 0; mi < 8; ++mi)                                            \
        af_[mi] = *(const s16x8*)&As[rb_ + aroff + mi * 512];                   \
      __builtin_amdgcn_s_setprio(1);                                            \
      _Pragma("unroll")                                                         \
      for (int mi = 0; mi < 8; ++mi)                                            \
        _Pragma("unroll")                                                       \
        for (int ni = 0; ni < 4; ++ni)                                          \
          acc[mi][ni] = __builtin_amdgcn_mfma_f32_16x16x32_bf16(                \
              af_[mi], bf_[ni], acc[mi][ni], 0, 0, 0);                          \
      __builtin_amdgcn_s_setprio(0);                                            \
    }                                                                           \
    asm volatile("s_waitcnt vmcnt(6) lgkmcnt(0)" ::: "memory");                 \
    __builtin_amdgcn_s_barrier();                                               \
  } while (0)

  #pragma unroll 1
  for (int kt = 0; kt < 64; kt += 4) {
    TILE(0, R0);
    TILE(1, R1);
    TILE(2, R0);
    TILE(3, R1);
  }
#undef TILE

  // ---- epilogue: relu(attn1 + attn2)·W_full, reduce over the wave's 64 cols,
  // atomic into scores. C/D map: col = c16, row = quad*4+rr (verified layout).
  int bfirst = m0 / LLEN;                       // block rows span <= 3 batches
  int bnd1 = (bfirst + 1) * LLEN, bnd2 = (bfirst + 2) * LLEN;
  int b1c = min(bfirst + 1, BATCH - 1), b2c = min(bfirst + 2, BATCH - 1);
  float wf[4], a2v0[4], a2v1[4], a2v2[4];
  #pragma unroll
  for (int ni = 0; ni < 4; ++ni) {
    int col = n0 + wc * 64 + ni * 16 + c16;
    wf[ni]   = W_full[col];
    a2v0[ni] = attn2p[(size_t)bfirst * A_DIM + col];
    a2v1[ni] = attn2p[(size_t)b1c * A_DIM + col];
    a2v2[ni] = attn2p[(size_t)b2c * A_DIM + col];
  }
  #pragma unroll
  for (int mi = 0; mi < 8; ++mi) {
    #pragma unroll
    for (int rr = 0; rr < 4; ++rr) {
      int row_g = m0 + wr * 128 + mi * 16 + quad * 4 + rr;
      float p = 0.f;
      #pragma unroll
      for (int ni = 0; ni < 4; ++ni) {
        float a2 = row_g >= bnd1 ? (row_g >= bnd2 ? a2v2[ni] : a2v1[ni]) : a2v0[ni];
        float v = acc[mi][ni][rr] + a2;
        v = fmaxf(v, 0.f);
        p = fmaf(v, wf[ni], p);
      }
      p += __shfl_xor(p, 1);
      p += __shfl_xor(p, 2);
      p += __shfl_xor(p, 4);
      p += __shfl_xor(p, 8);
      if (c16 == 0) atomicAdd(&scores[row_g], p);
    }
  }
}

// ---------------------------------------------------------------------------
// K3: softmax over L=196 per batch row (b_full dropped: softmax-invariant)
__global__ void softmax_kernel(const float* __restrict__ scores, float* __restrict__ alpha) {
  __shared__ float red[8];
  int b = blockIdx.x, t = threadIdx.x;
  float s = (t < LLEN) ? scores[b * LLEN + t] : -3.0e38f;
  float m = s;
  #pragma unroll
  for (int o = 1; o <= 32; o <<= 1) m = fmaxf(m, __shfl_xor(m, o));
  if ((t & 63) == 0) red[t >> 6] = m;
  __syncthreads();
  m = fmaxf(fmaxf(red[0], red[1]), fmaxf(red[2], red[3]));
  float e = (t < LLEN) ? expf(s - m) : 0.f;
  float sum = e;
  #pragma unroll
  for (int o = 1; o <= 32; o <<= 1) sum += __shfl_xor(sum, o);
  __syncthreads();
  if ((t & 63) == 0) red[4 + (t >> 6)] = sum;
  __syncthreads();
  sum = red[4] + red[5] + red[6] + red[7];
  if (t < LLEN) alpha[b * LLEN + t] = e / sum;
}

// ---------------------------------------------------------------------------
// K4: context from fp32 enc. Grid (2 f-chunks, 128 b, 4 L-chunks of 49), atomic.
__global__ void context_kernel(const float* __restrict__ enc, const float* __restrict__ alpha,
                               float* __restrict__ out) {
  __shared__ float al[49];
  int b = blockIdx.y, t = threadIdx.x;
  int l0 = blockIdx.z * 49;
  int f4 = blockIdx.x * 256 + t;
  if (t < 49) al[t] = alpha[b * LLEN + l0 + t];
  __syncthreads();
  const float4* e4 = (const float4*)enc + ((size_t)b * LLEN + l0) * (F_DIM / 4) + f4;
  float4 acc = {0.f, 0.f, 0.f, 0.f};
  #pragma unroll 7
  for (int l = 0; l < 49; ++l) {
    float4 v = e4[(size_t)l * (F_DIM / 4)];
    float a = al[l];
    acc.x = fmaf(v.x, a, acc.x);
    acc.y = fmaf(v.y, a, acc.y);
    acc.z = fmaf(v.z, a, acc.z);
    acc.w = fmaf(v.w, a, acc.w);
  }
  float* o = out + (size_t)b * F_DIM + f4 * 4;
  atomicAdd(o + 0, acc.x);
  atomicAdd(o + 1, acc.y);
  atomicAdd(o + 2, acc.z);
  atomicAdd(o + 3, acc.w);
}

// ---------------------------------------------------------------------------
extern "C" void kernel_launch(void* const* d_in, const int* in_sizes, int n_in,
                              void* d_out, int out_size, void* d_ws, size_t ws_size,
                              hipStream_t stream) {
  const float* enc    = (const float*)d_in[0];
  const float* hidden = (const float*)d_in[1];
  const float* W_enc  = (const float*)d_in[2];
  const float* b_enc  = (const float*)d_in[3];
  const float* W_hid  = (const float*)d_in[4];
  const float* b_hid  = (const float*)d_in[5];
  const float* W_full = (const float*)d_in[6];
  float* out = (float*)d_out;
  float* alpha_out = out + (size_t)BATCH * F_DIM;

  const size_t wt_bytes = (size_t)A_DIM * F_DIM * sizeof(u16);     // 4 MB
  const size_t a2_bytes = (size_t)BATCH * A_DIM * sizeof(float);   // 512 KB
  const size_t sc_bytes = (size_t)MROWS * sizeof(float);           // 100 KB
  char* ws = (char*)d_ws;
  u16*   WT     = (u16*)ws;
  float* attn2p = (float*)(ws + wt_bytes);
  float* scores = (float*)(ws + wt_bytes + a2_bytes);

  hipMemsetAsync(attn2p, 0, a2_bytes, stream);
  hipMemsetAsync(scores, 0, sc_bytes, stream);
  hipMemsetAsync(out, 0, (size_t)BATCH * F_DIM * sizeof(float), stream);

  wenc_cvt_kernel<<<dim3(F_DIM / 32, A_DIM / 32), 256, 0, stream>>>(W_enc, WT);
  attn2_kernel<<<dim3(A_DIM / 256, BATCH / 8, H_DIM / 128), 256, 0, stream>>>(hidden, W_hid, b_hid, b_enc, attn2p);
  // 13 groups x 32 (4 n-tiles x 8 m-tiles); guard kills mt >= 98.
  gemm_score<<<dim3(416), 512, 0, stream>>>(enc, WT, attn2p, W_full, scores);
  softmax_kernel<<<dim3(BATCH), 256, 0, stream>>>(scores, alpha_out);
  context_kernel<<<dim3(2, BATCH, 4), 256, 0, stream>>>(enc, alpha_out, out);
}

// Round 2
// 480.208 us; speedup vs baseline: 1.0400x; 1.0265x over previous
//
#include <hip/hip_runtime.h>
#include <hip/hip_bf16.h>

typedef unsigned short u16;
typedef short s16x8 __attribute__((ext_vector_type(8)));
typedef unsigned int u32x2 __attribute__((ext_vector_type(2)));
typedef float f32x4 __attribute__((ext_vector_type(4)));

#define F_DIM 2048
#define A_DIM 1024
#define H_DIM 1024
#define BATCH 128
#define LLEN  196
#define MROWS (BATCH * LLEN)   // 25088
#define MTILES (MROWS / 256)   // 98

__device__ __forceinline__ u16 f2b(float x) {
  union { float f; unsigned int u; } c; c.f = x;
  unsigned int r = (c.u + 0x7fffu + ((c.u >> 16) & 1u)) >> 16;  // RNE
  return (u16)r;
}

__device__ __forceinline__ unsigned int f2b_pk(float a, float b) {
  unsigned int r;
  asm volatile("v_cvt_pk_bf16_f32 %0, %1, %2" : "=v"(r) : "v"(a), "v"(b));
  return r;
}

__device__ __forceinline__ void gload_lds16(const void* g, void* l) {
  __builtin_amdgcn_global_load_lds((const __attribute__((address_space(1))) void*)g,
                                   (__attribute__((address_space(3))) void*)l, 16, 0, 0);
}

// ---------------------------------------------------------------------------
// K0: W_enc (2048x1024 fp32, k-major) -> WT (1024x2048 bf16, a-major)
__global__ void wenc_cvt_kernel(const float* __restrict__ W, u16* __restrict__ WT) {
  __shared__ float tile[32][33];
  int kb = blockIdx.x * 32, ab = blockIdx.y * 32;
  int t = threadIdx.x;
  int r = t >> 3, c = (t & 7) * 4;
  float4 v = *(const float4*)&W[(size_t)(kb + r) * A_DIM + ab + c];
  tile[r][c] = v.x; tile[r][c + 1] = v.y; tile[r][c + 2] = v.z; tile[r][c + 3] = v.w;
  __syncthreads();
  ushort4 o;
  o.x = f2b(tile[c + 0][r]);
  o.y = f2b(tile[c + 1][r]);
  o.z = f2b(tile[c + 2][r]);
  o.w = f2b(tile[c + 3][r]);
  *(ushort4*)&WT[(size_t)(ab + r) * F_DIM + kb + c] = o;
}

// ---------------------------------------------------------------------------
// K1: attn2p[b][a] = hidden[b]·W_hid[:,a] + b_hid[a] + b_enc[a]  (k-split 8, atomic)
__global__ void attn2_kernel(const float* __restrict__ hidden, const float* __restrict__ W_hid,
                             const float* __restrict__ b_hid, const float* __restrict__ b_enc,
                             float* __restrict__ attn2p) {
  __shared__ float hl[8][128];
  int t = threadIdx.x;
  int a  = blockIdx.x * 256 + t;
  int b0 = blockIdx.y * 8;
  int k0 = blockIdx.z * 128;
  {
    int j = t >> 5, kk = (t & 31) * 4;
    float4 v = *(const float4*)&hidden[(size_t)(b0 + j) * H_DIM + k0 + kk];
    hl[j][kk + 0] = v.x; hl[j][kk + 1] = v.y; hl[j][kk + 2] = v.z; hl[j][kk + 3] = v.w;
  }
  __syncthreads();
  float acc[8] = {0.f, 0.f, 0.f, 0.f, 0.f, 0.f, 0.f, 0.f};
  #pragma unroll 4
  for (int k = 0; k < 128; ++k) {
    float w = W_hid[(size_t)(k0 + k) * A_DIM + a];
    #pragma unroll
    for (int j = 0; j < 8; ++j) acc[j] = fmaf(hl[j][k], w, acc[j]);
  }
  if (blockIdx.z == 0) {
    float bias = b_hid[a] + b_enc[a];
    #pragma unroll
    for (int j = 0; j < 8; ++j) acc[j] += bias;
  }
  #pragma unroll
  for (int j = 0; j < 8; ++j) atomicAdd(&attn2p[(size_t)(b0 + j) * A_DIM + a], acc[j]);
}

// ---------------------------------------------------------------------------
// K2: fused GEMM + score, m201-style 8-phase schedule (plain HIP port).
// BM=BN=256, BK=64, 8 waves (2M x 4N), wave tile 128x64, acc[8][4].
// Per phase: {ds_read quadrant frags || stage one half-tile} -> barrier ->
// lgkmcnt(0) -> setprio(1) -> 16 MFMA -> setprio(0) -> barrier.
// Counted vmcnt(8) ONLY at phases 4 and 8 (B-gloads stay in flight 3-4
// phases; never drain to 0 in the loop).
// A (enc fp32) is reg-staged: global_load_dwordx4 two phases before the
// cvt_pk+ds_write_b64, write 3+ phases before first read.
// T2 XOR swizzle (granule ^= row&7, 8x16B granules per 128B row) on both
// tiles: reads and writes are 2-way -> conflict-free.
__global__ __launch_bounds__(512, 2) void gemm_score(
    const float* __restrict__ enc, const u16* __restrict__ WT,
    const float* __restrict__ attn2p, const float* __restrict__ W_full,
    float* __restrict__ scores) {
  __shared__ __align__(16) u16 As[2 * 16384];   // 2 bufs x 256 rows x 64 k bf16 = 64 KB
  __shared__ __align__(16) u16 Bs[2 * 16384];   // 64 KB

  int i = blockIdx.x;
  int g = i >> 5, r = i & 31;
  int y = r >> 3, gi = r & 7;
  int mt = g * 8 + gi;
  if (mt >= MTILES) return;              // uniform per-block: no barrier hazard
  int m0 = mt * 256, n0 = y * 256;
  int t = threadIdx.x;
  int lane = t & 63, wave = t >> 6;
  int wr = wave >> 2, wc = wave & 3;     // wave grid 2M x 4N
  int c16 = lane & 15, quad = lane >> 4;

  // ---- staging addresses -------------------------------------------------
  // A loads: thread covers row t>>2 (of a 128-row half), 4 sites of 4 floats
  // at k-local (t&3)*4 + s*16.
  const float* aP = enc + (size_t)(m0 + (t >> 2)) * F_DIM + (t & 3) * 4;
  // A writes: row (t>>2), granule g_s = s*2 + ((t&3)>>1), XOR key (t>>2)&7,
  // half-granule (t&3)&1. Element offsets precomputed.
  int awo[4];
  #pragma unroll
  for (int s = 0; s < 4; ++s)
    awo[s] = (t >> 2) * 64 + ((t & 3) & 1) * 4
           + (((s * 2 + ((t & 3) >> 1)) ^ ((t >> 2) & 7)) * 8);
  // B gload_lds: site s covers rows s*64 + (t>>3); source granule
  // pre-swizzled so linear LDS dest == swizzled layout.
  const u16* bgp = WT + (size_t)(n0 + (t >> 3)) * F_DIM + ((t & 7) ^ ((t >> 3) & 7)) * 8;

  // ---- fragment read offsets (u16 elems) ---------------------------------
  const int akey = c16 & 7;
  int gsw[2];
  gsw[0] = ((0 * 4 + quad) ^ akey) * 8;
  gsw[1] = ((1 * 4 + quad) ^ akey) * 8;
  const int aro = (wr * 128 + c16) * 64;
  const int bro = (wc * 64 + c16) * 64;

  f32x4 acc[8][4];
  #pragma unroll
  for (int mi = 0; mi < 8; ++mi)
    #pragma unroll
    for (int ni = 0; ni < 4; ++ni) acc[mi][ni] = (f32x4){0.f, 0.f, 0.f, 0.f};

  s16x8 af[4][2], bf[2][2];
  float4 RAlo[4], RAhi[4];

#define ALD(RX, half, kt_) do {                                                 \
    const float* p_ = aP + (size_t)(half) * 128 * F_DIM + (kt_) * 64;           \
    RX[0] = *(const float4*)(p_);                                               \
    RX[1] = *(const float4*)(p_ + 16);                                          \
    RX[2] = *(const float4*)(p_ + 32);                                          \
    RX[3] = *(const float4*)(p_ + 48);                                          \
  } while (0)

#define AWR(RX, cb, half) do {                                                  \
    _Pragma("unroll")                                                           \
    for (int s_ = 0; s_ < 4; ++s_) {                                            \
      u32x2 w_; w_.x = f2b_pk(RX[s_].x, RX[s_].y);                              \
      w_.y = f2b_pk(RX[s_].z, RX[s_].w);                                        \
      *(u32x2*)&As[(cb) * 16384 + (half) * 8192 + awo[s_]] = w_;                \
    }                                                                           \
  } while (0)

#define BGL(cb, kt_) do {                                                       \
    _Pragma("unroll")                                                           \
    for (int s_ = 0; s_ < 4; ++s_)                                              \
      gload_lds16(bgp + (size_t)s_ * 64 * F_DIM + (size_t)(kt_) * 64,           \
                  Bs + (cb) * 16384 + s_ * 4096 + wave * 512);                  \
  } while (0)

#define DSRA(cb, mh)                                                            \
    _Pragma("unroll")                                                           \
    for (int i_ = 0; i_ < 4; ++i_)                                              \
      _Pragma("unroll")                                                         \
      for (int h_ = 0; h_ < 2; ++h_)                                            \
        af[i_][h_] = *(const s16x8*)&As[(cb) * 16384 + aro                      \
                                        + ((mh) * 4 + i_) * 1024 + gsw[h_]];

#define DSRB(cb, nh)                                                            \
    _Pragma("unroll")                                                           \
    for (int j_ = 0; j_ < 2; ++j_)                                              \
      _Pragma("unroll")                                                         \
      for (int h_ = 0; h_ < 2; ++h_)                                            \
        bf[j_][h_] = *(const s16x8*)&Bs[(cb) * 16384 + bro                      \
                                        + ((nh) * 2 + j_) * 1024 + gsw[h_]];

#define GATE8 asm volatile("s_waitcnt vmcnt(8)" ::: "memory")
#define NOGATE ((void)0)

#define PHASE(cb, mh, nh, GATE, ...) do {                                       \
    if ((nh) == 0) { DSRA(cb, mh); }                                            \
    DSRB(cb, nh);                                                               \
    __VA_ARGS__                                                                 \
    GATE;                                                                       \
    __builtin_amdgcn_s_barrier();                                               \
    asm volatile("s_waitcnt lgkmcnt(0)" ::: "memory");                          \
    __builtin_amdgcn_s_setprio(1);                                              \
    _Pragma("unroll")                                                           \
    for (int i_ = 0; i_ < 4; ++i_)                                              \
      _Pragma("unroll")                                                         \
      for (int j_ = 0; j_ < 2; ++j_)                                            \
        _Pragma("unroll")                                                       \
        for (int h_ = 0; h_ < 2; ++h_)                                          \
          acc[(mh) * 4 + i_][(nh) * 2 + j_] =                                   \
              __builtin_amdgcn_mfma_f32_16x16x32_bf16(                          \
                  af[i_][h_], bf[j_][h_],                                       \
                  acc[(mh) * 4 + i_][(nh) * 2 + j_], 0, 0, 0);                  \
    __builtin_amdgcn_s_setprio(0);                                              \
    __builtin_amdgcn_s_barrier();                                               \
  } while (0)

  // ---- prologue: buf0 <- tile0 (A,B); buf1 <- A-lo(1); regs <- A-hi(1).
  BGL(0, 0);
  ALD(RAlo, 0, 0);
  ALD(RAhi, 1, 0);
  AWR(RAlo, 0, 0);
  AWR(RAhi, 0, 1);
  ALD(RAlo, 0, 1);
  AWR(RAlo, 1, 0);
  ALD(RAhi, 1, 1);                       // A-hi(1) stays in regs for ph1
  asm volatile("s_waitcnt vmcnt(0) lgkmcnt(0)" ::: "memory");
  __builtin_amdgcn_s_barrier();

  // ---- main loop: 32 K-tiles = 16 iterations of 8 phases -----------------
  #pragma unroll 1
  for (int it = 0; it < 16; ++it) {
    int tt = 2 * it;
    int t2 = min(tt + 2, 31), t3 = min(tt + 3, 31);
    // tile tt in buf0
    PHASE(0, 0, 0, NOGATE, AWR(RAhi, 1, 1); BGL(1, tt + 1);); // wr A-hi(t+1); gl B(t+1)
    PHASE(0, 0, 1, NOGATE, ALD(RAlo, 0, t2););                // ld A-lo(t+2)
    PHASE(0, 1, 0, NOGATE, ALD(RAhi, 1, t2););                // ld A-hi(t+2)
    PHASE(0, 1, 1, GATE8,  AWR(RAlo, 0, 0););                 // wr A-lo(t+2); gate B(t+1)
    // tile tt+1 in buf1
    PHASE(1, 0, 0, NOGATE, AWR(RAhi, 0, 1); BGL(0, t2););     // wr A-hi(t+2); gl B(t+2)
    PHASE(1, 0, 1, NOGATE, ALD(RAlo, 0, t3););                // ld A-lo(t+3)
    PHASE(1, 1, 0, NOGATE, ALD(RAhi, 1, t3););                // ld A-hi(t+3)
    PHASE(1, 1, 1, GATE8,  AWR(RAlo, 1, 0););                 // wr A-lo(t+3); gate B(t+2)
  }
#undef PHASE
#undef DSRA
#undef DSRB
#undef BGL
#undef AWR
#undef ALD

  // ---- epilogue: relu(attn1 + attn2)·W_full, 16-lane reduce, atomic score.
  int bfirst = m0 / LLEN;                       // block rows span <= 3 batches
  int bnd1 = (bfirst + 1) * LLEN, bnd2 = (bfirst + 2) * LLEN;
  int b1c = min(bfirst + 1, BATCH - 1), b2c = min(bfirst + 2, BATCH - 1);
  float wf[4], a2v0[4], a2v1[4], a2v2[4];
  #pragma unroll
  for (int ni = 0; ni < 4; ++ni) {
    int col = n0 + wc * 64 + ni * 16 + c16;
    wf[ni]   = W_full[col];
    a2v0[ni] = attn2p[(size_t)bfirst * A_DIM + col];
    a2v1[ni] = attn2p[(size_t)b1c * A_DIM + col];
    a2v2[ni] = attn2p[(size_t)b2c * A_DIM + col];
  }
  #pragma unroll
  for (int mi = 0; mi < 8; ++mi) {
    #pragma unroll
    for (int rr = 0; rr < 4; ++rr) {
      int row_g = m0 + wr * 128 + mi * 16 + quad * 4 + rr;
      float p = 0.f;
      #pragma unroll
      for (int ni = 0; ni < 4; ++ni) {
        float a2 = row_g >= bnd1 ? (row_g >= bnd2 ? a2v2[ni] : a2v1[ni]) : a2v0[ni];
        float v = acc[mi][ni][rr] + a2;
        v = fmaxf(v, 0.f);
        p = fmaf(v, wf[ni], p);
      }
      p += __shfl_xor(p, 1);
      p += __shfl_xor(p, 2);
      p += __shfl_xor(p, 4);
      p += __shfl_xor(p, 8);
      if (c16 == 0) atomicAdd(&scores[row_g], p);
    }
  }
}

// ---------------------------------------------------------------------------
// K3: softmax over L=196 per batch row (b_full dropped: softmax-invariant)
__global__ void softmax_kernel(const float* __restrict__ scores, float* __restrict__ alpha) {
  __shared__ float red[8];
  int b = blockIdx.x, t = threadIdx.x;
  float s = (t < LLEN) ? scores[b * LLEN + t] : -3.0e38f;
  float m = s;
  #pragma unroll
  for (int o = 1; o <= 32; o <<= 1) m = fmaxf(m, __shfl_xor(m, o));
  if ((t & 63) == 0) red[t >> 6] = m;
  __syncthreads();
  m = fmaxf(fmaxf(red[0], red[1]), fmaxf(red[2], red[3]));
  float e = (t < LLEN) ? expf(s - m) : 0.f;
  float sum = e;
  #pragma unroll
  for (int o = 1; o <= 32; o <<= 1) sum += __shfl_xor(sum, o);
  __syncthreads();
  if ((t & 63) == 0) red[4 + (t >> 6)] = sum;
  __syncthreads();
  sum = red[4] + red[5] + red[6] + red[7];
  if (t < LLEN) alpha[b * LLEN + t] = e / sum;
}

// ---------------------------------------------------------------------------
// K4: context, non-atomic: block owns (b, f-half of 1024 floats), loops all
// 196 L rows. Exact-once read of enc (205 MB), direct float4 store, no memset.
__global__ __launch_bounds__(256) void context_kernel(
    const float* __restrict__ enc, const float* __restrict__ alpha,
    float* __restrict__ out) {
  __shared__ float al[LLEN];
  int b = blockIdx.y, t = threadIdx.x;
  if (t < LLEN) al[t] = alpha[b * LLEN + t];
  __syncthreads();
  int f4 = blockIdx.x * 256 + t;   // 0..511
  const float4* e4 = (const float4*)enc + (size_t)b * LLEN * (F_DIM / 4) + f4;
  float4 acc = {0.f, 0.f, 0.f, 0.f};
  #pragma unroll 4
  for (int l = 0; l < LLEN; ++l) {
    float4 v = e4[(size_t)l * (F_DIM / 4)];
    float a = al[l];
    acc.x = fmaf(v.x, a, acc.x);
    acc.y = fmaf(v.y, a, acc.y);
    acc.z = fmaf(v.z, a, acc.z);
    acc.w = fmaf(v.w, a, acc.w);
  }
  *(float4*)(out + (size_t)b * F_DIM + f4 * 4) = acc;
}

// ---------------------------------------------------------------------------
extern "C" void kernel_launch(void* const* d_in, const int* in_sizes, int n_in,
                              void* d_out, int out_size, void* d_ws, size_t ws_size,
                              hipStream_t stream) {
  const float* enc    = (const float*)d_in[0];
  const float* hidden = (const float*)d_in[1];
  const float* W_enc  = (const float*)d_in[2];
  const float* b_enc  = (const float*)d_in[3];
  const float* W_hid  = (const float*)d_in[4];
  const float* b_hid  = (const float*)d_in[5];
  const float* W_full = (const float*)d_in[6];
  float* out = (float*)d_out;
  float* alpha_out = out + (size_t)BATCH * F_DIM;

  const size_t wt_bytes = (size_t)A_DIM * F_DIM * sizeof(u16);     // 4 MB
  const size_t a2_bytes = (size_t)BATCH * A_DIM * sizeof(float);   // 512 KB
  const size_t sc_bytes = (size_t)MROWS * sizeof(float);           // 100 KB
  char* ws = (char*)d_ws;
  u16*   WT     = (u16*)ws;
  float* attn2p = (float*)(ws + wt_bytes);
  float* scores = (float*)(ws + wt_bytes + a2_bytes);

  // attn2p and scores are contiguous: single memset. out needs no memset
  // (context writes directly).
  hipMemsetAsync(attn2p, 0, a2_bytes + sc_bytes, stream);

  wenc_cvt_kernel<<<dim3(F_DIM / 32, A_DIM / 32), 256, 0, stream>>>(W_enc, WT);
  attn2_kernel<<<dim3(A_DIM / 256, BATCH / 8, H_DIM / 128), 256, 0, stream>>>(hidden, W_hid, b_hid, b_enc, attn2p);
  // 13 groups x 32 (4 n-tiles x 8 m-tiles); guard kills mt >= 98.
  gemm_score<<<dim3(416), 512, 0, stream>>>(enc, WT, attn2p, W_full, scores);
  softmax_kernel<<<dim3(BATCH), 256, 0, stream>>>(scores, alpha_out);
  context_kernel<<<dim3(2, BATCH), 256, 0, stream>>>(enc, alpha_out, out);
}